// Round 20
// baseline (2367.692 us; speedup 1.0000x reference)
//
#include <hip/hip_runtime.h>
#include <hip/hip_fp16.h>
#include <math.h>

#define TT 833          // output timesteps
#define GDIM 1024       // 4*H gates

typedef _Float16 f16x8 __attribute__((ext_vector_type(8)));
typedef float    f32x4 __attribute__((ext_vector_type(4)));

#if __has_builtin(__builtin_amdgcn_rcpf)
__device__ __forceinline__ float frcp(float x){ return __builtin_amdgcn_rcpf(x); }
#else
__device__ __forceinline__ float frcp(float x){ return 1.f/x; }
#endif

#if __has_builtin(__builtin_amdgcn_sdot4)
__device__ __forceinline__ int sdot4(unsigned a, unsigned b, int c){
  return __builtin_amdgcn_sdot4((int)a, (int)b, c, false);
}
#else
__device__ __forceinline__ int sdot4(unsigned a, unsigned b, int c){
  int ai = (int)a, bi = (int)b;
  c += ((ai<<24)>>24)*((bi<<24)>>24);
  c += ((ai<<16)>>24)*((bi<<16)>>24);
  c += ((ai<<8)>>24)*((bi<<8)>>24);
  c += (ai>>24)*(bi>>24);
  return c;
}
#endif

// LDS-only barrier (r17): keeps per-step global h-stores off the serial path.
__device__ __forceinline__ void lds_barrier(){
  asm volatile("s_waitcnt lgkmcnt(0)" ::: "memory");
  __builtin_amdgcn_s_barrier();
  __builtin_amdgcn_sched_barrier(0);
}

// Gate-row permutation: permuted row p <-> original row (p&3)*256 + (p>>2).
// Cell-per-thread layout: thread t owns permuted rows 4t..4t+3 = ALL FOUR GATES of
// cell t -> cell update fully thread-local (no shuffles, no idle lanes); 4 waves.

// ---------------- level smoothing scan (float4-batched) ----------------
__global__ void levels_k(const float* __restrict__ train, const float* __restrict__ ism,
                         float* __restrict__ levs){
  int b = threadIdx.x;
  if (b >= 32) return;
  float a = 1.f/(1.f+expf(-ism[0]));
  const float4* tr4 = reinterpret_cast<const float4*>(train + b*1024);
  float4* lv4 = reinterpret_cast<float4*>(levs + b*1024);
  float lev = 0.f;
  for (int i = 0; i < 256; ++i){
    float4 v = tr4[i];
    float4 o;
    if (i == 0) o.x = lev = fmaxf(v.x, 0.1f);
    else        o.x = lev = fmaxf(fmaf(a, v.x, (1.f-a)*lev), 0.1f);
    o.y = lev = fmaxf(fmaf(a, v.y, (1.f-a)*lev), 0.1f);
    o.z = lev = fmaxf(fmaf(a, v.z, (1.f-a)*lev), 0.1f);
    o.w = lev = fmaxf(fmaf(a, v.w, (1.f-a)*lev), 0.1f);
    lv4[i] = o;
  }
}

// ---------------- normalized input windows x0[t*32+b][192] fp16, zero-padded ----------------
__global__ void win_x_k(const float* __restrict__ train, const float* __restrict__ levs,
                        __half* __restrict__ x0){
  int idx = blockIdx.x*256 + threadIdx.x;   // exactly 833*32*192
  int i = idx % 192;
  int r = idx / 192;       // t*32+b
  int b = r & 31;
  int t = r >> 5;
  x0[idx] = (i < 168) ? __float2half(train[b*1024 + t + i] / levs[b*1024 + t + 167])
                      : __float2half(0.f);
}

// ---------------- out_win -> d_out second half ----------------
__global__ void win_out_k(const float* __restrict__ train, const float* __restrict__ levs,
                          float* __restrict__ ow){
  int idx = blockIdx.x*256 + threadIdx.x;   // exactly 833*32*24
  int o = idx % 24;
  int r = idx / 24;
  int b = r & 31;
  int t = r >> 5;
  ow[idx] = train[b*1024 + 168 + t + o] / levs[b*1024 + t + 167];
}

// ---------------- permute wih rows -> fp16 (Kpad stride, zero-pad) + fuse biases ----------
__global__ void permw_k(const float* __restrict__ wih, const float* __restrict__ bih,
                        const float* __restrict__ bhh, __half* __restrict__ wP,
                        float* __restrict__ bP, int K, int Kpad){
  int t = blockIdx.x;                       // 1024 rows
  int g = ((t & 3) << 8) + (t >> 2);
  for (int k = threadIdx.x; k < Kpad; k += 256)
    wP[(size_t)t*Kpad + k] = (k < K) ? __float2half(wih[(size_t)g*K + k]) : __float2half(0.f);
  if (threadIdx.x == 0) bP[t] = bih[g] + bhh[g];
}

// ---------------- fp32 -> fp16 convert (one-time, nl_w) ----------------
__global__ void cvth_k(const float* __restrict__ s, __half* __restrict__ d, int n){
  int i = blockIdx.x*256 + threadIdx.x;
  if (i < n) d[i] = __float2half(s[i]);
}

// ---------------- quantize whh -> int8 wq[k16][1024] permuted rows (+ scale) ----------------
__global__ void packq_k(const float* __restrict__ w, uint4* __restrict__ wq,
                        float* __restrict__ sc){
  int t = blockIdx.x*256 + threadIdx.x;     // 1024 rows
  if (t >= 1024) return;
  int g = ((t & 3) << 8) + (t >> 2);
  const float* row = w + (size_t)g*256;
  float amax = 0.f;
  for (int k = 0; k < 256; ++k) amax = fmaxf(amax, fabsf(row[k]));
  amax = fmaxf(amax, 1e-20f);
  float s = amax/127.f, inv = 127.f/amax;
  sc[t] = s;
  for (int k16 = 0; k16 < 16; ++k16){
    union { uint4 u; signed char b[16]; } r;
    #pragma unroll
    for (int j = 0; j < 16; ++j){
      float q = rintf(row[k16*16 + j]*inv);
      q = fminf(fmaxf(q, -127.f), 127.f);
      r.b[j] = (signed char)q;
    }
    wq[(size_t)k16*1024 + t] = r.u;
  }
}

// ---------------- MFMA fp16 GEMM, 256x128 tile, 512 thr / 8 waves (4x2) ----------------
__global__ __launch_bounds__(512) void proj_mfma(
    const _Float16* __restrict__ A, const _Float16* __restrict__ W,
    const float* __restrict__ b1,
    void* __restrict__ C, int Mout, int K, int N, int dil, int act, int outHalf)
{
  __shared__ _Float16 As[256*40];
  __shared__ _Float16 Bs[128*40];
  const int tid = threadIdx.x;
  const int lane = tid & 63;
  const int w = tid >> 6, wr = w >> 1, wc = w & 1;   // 4x2 wave grid
  const int m0 = blockIdx.y << 8, n0 = blockIdx.x << 7;

  const int rowA = tid >> 1;
  const int halfsel = tid & 1;
  int srcrow;
  {
    int m = m0 + rowA;
    if (dil == 0) srcrow = (m < Mout) ? m : -1;
    else {
      int rows = dil << 5;
      int jj = m / rows;
      int q = m - jj*rows;
      int t = jj*dil + (q >> 5);
      srcrow = (t < TT) ? ((t << 5) + (q & 31)) : -1;
    }
  }
  const int rowB = (tid & 255) >> 1;
  const int nrow = n0 + rowB;

  f32x4 acc[4][4];
  #pragma unroll
  for (int i = 0; i < 4; ++i)
    #pragma unroll
    for (int j = 0; j < 4; ++j) acc[i][j] = (f32x4){0.f,0.f,0.f,0.f};

  const int nkt = K >> 5;
  for (int kt = 0; kt < nkt; ++kt){
    const int k0 = (kt << 5) + halfsel*16;
    {
      union { uint4 u[2]; _Float16 h[16]; } tmp;
      if (srcrow >= 0){
        const uint4* s = reinterpret_cast<const uint4*>(A + (size_t)srcrow*K + k0);
        tmp.u[0] = s[0]; tmp.u[1] = s[1];
      } else {
        tmp.u[0] = make_uint4(0,0,0,0); tmp.u[1] = make_uint4(0,0,0,0);
      }
      uint4* dst = reinterpret_cast<uint4*>(&As[rowA*40 + halfsel*16]);
      dst[0] = tmp.u[0]; dst[1] = tmp.u[1];
    }
    if (tid < 256){
      const uint4* s = reinterpret_cast<const uint4*>(W + (size_t)nrow*K + k0);
      uint4* dst = reinterpret_cast<uint4*>(&Bs[rowB*40 + halfsel*16]);
      dst[0] = s[0]; dst[1] = s[1];
    }
    __syncthreads();
    {
      const int kg = lane >> 4, r16 = lane & 15;
      f16x8 af[4], bf[4];
      #pragma unroll
      for (int mi = 0; mi < 4; ++mi)
        af[mi] = *reinterpret_cast<const f16x8*>(&As[(wr*64 + mi*16 + r16)*40 + kg*8]);
      #pragma unroll
      for (int nj = 0; nj < 4; ++nj)
        bf[nj] = *reinterpret_cast<const f16x8*>(&Bs[(wc*64 + nj*16 + r16)*40 + kg*8]);
      #pragma unroll
      for (int mi = 0; mi < 4; ++mi)
        #pragma unroll
        for (int nj = 0; nj < 4; ++nj)
          acc[mi][nj] = __builtin_amdgcn_mfma_f32_16x16x32_f16(af[mi], bf[nj], acc[mi][nj], 0, 0, 0);
    }
    __syncthreads();
  }
  #pragma unroll
  for (int mi = 0; mi < 4; ++mi){
    #pragma unroll
    for (int p = 0; p < 4; ++p){
      int mrow = m0 + wr*64 + mi*16 + (lane >> 4)*4 + p;
      if (mrow >= Mout) continue;
      #pragma unroll
      for (int nj = 0; nj < 4; ++nj){
        int ncol = n0 + wc*64 + nj*16 + (lane & 15);
        float v = acc[mi][nj][p] + b1[ncol];
        if (act) v = tanhf(v);
        if (outHalf) reinterpret_cast<__half*>(C)[(size_t)mrow*N + ncol] = __float2half(v);
        else reinterpret_cast<float*>(C)[(size_t)mrow*N + ncol] = v;
      }
    }
  }
}

// ---------------- cell-per-thread int8 sdot4 LSTM: 256 threads, 4 gate rows/thread -------
// Thread t owns permuted rows 4t..4t+3 = gates {i,f,g,o} of cell t: update is fully
// thread-local (zero shuffles, all lanes active). 4 waves (1/SIMD) halve per-SIMD
// issue + LDS-read instructions vs the r15 512-thread form. Weights = 64 uint4 =
// 256 VGPR; launch_bounds(256,1) grants the 512-reg budget (watch spill: FETCH explosion).
template<int NR>
__global__ __launch_bounds__(256, 1) void srecc_k(
    const uint4* __restrict__ wq, const float* __restrict__ scale,
    const __half* __restrict__ Gin,
    __half* __restrict__ outh, float* __restrict__ outf,
    int nsteps, int d, int rowsTotal)
{
  __shared__ __align__(16) unsigned int hq[2][NR][64];
  const int t = threadIdx.x;        // cell index 0..255
  const int q0 = blockIdx.x*NR;
  float sg[4];
  #pragma unroll
  for (int g = 0; g < 4; ++g) sg[g] = scale[4*t + g]*(1.f/127.f);
  uint4 w_[4][16];
  #pragma unroll
  for (int k = 0; k < 16; ++k)
    #pragma unroll
    for (int g = 0; g < 4; ++g)
      w_[g][k] = wq[(size_t)k*1024 + 4*t + g];
  float c[NR];
  #pragma unroll
  for (int rr = 0; rr < NR; ++rr) c[rr] = 0.f;
  for (int e = t; e < 2*NR*64; e += 256) (&hq[0][0][0])[e] = 0u;
  __syncthreads();

  for (int step = 0; step < nsteps; ++step){
    const int cur = step & 1;
    #pragma unroll
    for (int rr = 0; rr < NR; ++rr){
      const __half* gb = Gin + ((size_t)step*rowsTotal + q0 + rr)*GDIM + 4*t;
      uint2 gu = *reinterpret_cast<const uint2*>(gb);
      union { unsigned u; __half2 h2; } glo, ghi;
      glo.u = gu.x; ghi.u = gu.y;
      float gi = __half2float(__low2half(glo.h2));
      float gf = __half2float(__high2half(glo.h2));
      float gg = __half2float(__low2half(ghi.h2));
      float go = __half2float(__high2half(ghi.h2));
      int a0 = 0, a1 = 0, a2 = 0, a3 = 0;
      #pragma unroll
      for (int k = 0; k < 16; ++k){
        uint4 h4 = *reinterpret_cast<const uint4*>(&hq[cur][rr][4*k]);
        a0 = sdot4(w_[0][k].x, h4.x, a0); a0 = sdot4(w_[0][k].y, h4.y, a0);
        a0 = sdot4(w_[0][k].z, h4.z, a0); a0 = sdot4(w_[0][k].w, h4.w, a0);
        a1 = sdot4(w_[1][k].x, h4.x, a1); a1 = sdot4(w_[1][k].y, h4.y, a1);
        a1 = sdot4(w_[1][k].z, h4.z, a1); a1 = sdot4(w_[1][k].w, h4.w, a1);
        a2 = sdot4(w_[2][k].x, h4.x, a2); a2 = sdot4(w_[2][k].y, h4.y, a2);
        a2 = sdot4(w_[2][k].z, h4.z, a2); a2 = sdot4(w_[2][k].w, h4.w, a2);
        a3 = sdot4(w_[3][k].x, h4.x, a3); a3 = sdot4(w_[3][k].y, h4.y, a3);
        a3 = sdot4(w_[3][k].z, h4.z, a3); a3 = sdot4(w_[3][k].w, h4.w, a3);
      }
      float pi = fmaf((float)a0, sg[0], gi);
      float pf = fmaf((float)a1, sg[1], gf);
      float pg = fmaf((float)a2, sg[2], gg);
      float po = fmaf((float)a3, sg[3], go);
      float iv = frcp(1.f + __expf(-pi));
      float fv = frcp(1.f + __expf(-pf));
      float gv = fmaf(2.f, frcp(1.f + __expf(-2.f*pg)), -1.f);
      float ov = frcp(1.f + __expf(-po));
      float cn = fmaf(fv, c[rr], iv*gv);
      c[rr] = cn;
      float e2 = __expf(-2.f*cn);
      float h = ov*(1.f - e2)*frcp(1.f + e2);
      int qh = (int)rintf(h*127.f);
      reinterpret_cast<signed char*>(&hq[cur^1][rr][0])[t] = (signed char)qh;
      int q = q0 + rr;
      int tg = step*d + (q >> 5);
      if (tg < TT){
        size_t oi = ((size_t)tg*32 + (q & 31))*256 + t;
        outh[oi] = __float2half(h);
        if (outf) outf[oi] = h;
      }
    }
    lds_barrier();
  }
}

// ---------------- streamed-weight variant (NR=8, d=64), residual, fp16 out --------------
template<int NR>
__global__ __launch_bounds__(1024) void srecq_k(
    const uint4* __restrict__ wq, const float* __restrict__ scale,
    const __half* __restrict__ Gin,
    __half* __restrict__ outh, const float* __restrict__ res,
    int nsteps, int d, int rowsTotal)
{
  __shared__ __align__(16) unsigned int hq[2][NR][64];
  const int tid = threadIdx.x;
  const int lane = tid & 63;
  const int base = lane & ~3;
  const int kg = tid & 3;
  const int j = tid >> 2;
  const int q0 = blockIdx.x*NR;
  const float sg = scale[tid]*(1.f/127.f);
  float c[NR];
  #pragma unroll
  for (int rr = 0; rr < NR; ++rr) c[rr] = 0.f;
  for (int e = tid; e < 2*NR*64; e += 1024) (&hq[0][0][0])[e] = 0u;
  __syncthreads();

  for (int step = 0; step < nsteps; ++step){
    const int cur = step & 1;
    float gin[NR];
    const __half* gbase = Gin + ((size_t)step*rowsTotal + q0)*GDIM;
    #pragma unroll
    for (int rr = 0; rr < NR; ++rr) gin[rr] = __half2float(gbase[rr*GDIM + tid]);
    int acc[NR];
    #pragma unroll
    for (int rr = 0; rr < NR; ++rr) acc[rr] = 0;
    #pragma unroll 4
    for (int k16 = 0; k16 < 16; ++k16){
      uint4 w = wq[(size_t)k16*1024 + tid];
      #pragma unroll
      for (int rr = 0; rr < NR; ++rr){
        uint4 h4 = *reinterpret_cast<const uint4*>(&hq[cur][rr][4*k16]);
        acc[rr] = sdot4(w.x, h4.x, acc[rr]);
        acc[rr] = sdot4(w.y, h4.y, acc[rr]);
        acc[rr] = sdot4(w.z, h4.z, acc[rr]);
        acc[rr] = sdot4(w.w, h4.w, acc[rr]);
      }
    }
    #pragma unroll
    for (int rr = 0; rr < NR; ++rr){
      float p = fmaf((float)acc[rr], sg, gin[rr]);
      float px = (kg == 2) ? p + p : p;
      float sv = frcp(1.f + __expf(-px));
      float a = (kg == 2) ? fmaf(2.f, sv, -1.f) : sv;
      float iv = __shfl(a, base + 0);
      float fv = __shfl(a, base + 1);
      float gv = __shfl(a, base + 2);
      float ov = __shfl(a, base + 3);
      float cn = fmaf(fv, c[rr], iv*gv);
      c[rr] = cn;
      float e2 = __expf(-2.f*cn);
      float h = ov*(1.f - e2)*frcp(1.f + e2);
      if (kg == 0){
        int qh = (int)rintf(h*127.f);
        reinterpret_cast<signed char*>(&hq[cur^1][rr][0])[j] = (signed char)qh;
        int q = q0 + rr;
        int tg = step*d + (q >> 5);
        if (tg < TT){
          size_t oi = ((size_t)tg*32 + (q & 31))*256 + j;
          outh[oi] = __float2half(h + res[oi]);
        }
      }
    }
    lds_barrier();
  }
}

// ---------------- scoring head (fp16 xt): pred[m][24] = xt[m][:] . sc_w[n][:] + sc_b ------
__global__ __launch_bounds__(256) void sc_head(const __half* __restrict__ xt, const float* __restrict__ w,
                        const float* __restrict__ bias, float* __restrict__ outp, int M){
  __shared__ float arow[8][256];
  int m0 = blockIdx.x << 3;
  int tid = threadIdx.x;
  #pragma unroll
  for (int i = 0; i < 8; ++i){
    int e = tid + (i << 8);
    int r = e >> 8, k = e & 255;
    arow[r][k] = (m0 + r < M) ? __half2float(xt[(size_t)(m0 + r)*256 + k]) : 0.f;
  }
  __syncthreads();
  int r = tid >> 5, n = tid & 31;
  if (n < 24 && (m0 + r) < M){
    float acc = bias[n];
    const float* wr = w + n*256;
    #pragma unroll 8
    for (int k = 0; k < 256; ++k) acc = fmaf(arow[r][k], wr[k], acc);
    outp[(size_t)(m0 + r)*24 + n] = acc;
  }
}

extern "C" void kernel_launch(void* const* d_in, const int* in_sizes, int n_in,
                              void* d_out, int out_size, void* d_ws, size_t ws_size,
                              hipStream_t stream){
  const float* train = (const float*)d_in[0];
  const float* ism   = (const float*)d_in[4];
  const float* wih[4] = {(const float*)d_in[5], (const float*)d_in[9], (const float*)d_in[13], (const float*)d_in[17]};
  const float* whh[4] = {(const float*)d_in[6], (const float*)d_in[10], (const float*)d_in[14], (const float*)d_in[18]};
  const float* bih[4] = {(const float*)d_in[7], (const float*)d_in[11], (const float*)d_in[15], (const float*)d_in[19]};
  const float* bhh[4] = {(const float*)d_in[8], (const float*)d_in[12], (const float*)d_in[16], (const float*)d_in[20]};
  const float* nl_w = (const float*)d_in[21];
  const float* nl_b = (const float*)d_in[22];
  const float* sc_w = (const float*)d_in[23];
  const float* sc_b = (const float*)d_in[24];
  float* out = (float*)d_out;

  float* ws = (float*)d_ws;
  size_t off = 0;
  float* levs = ws + off;   off += 32768;
  uint4* wqk[4];
  for (int l = 0; l < 4; ++l){ wqk[l] = (uint4*)(ws + off); off += 65536; }   // 256KB each
  float* sck[4];
  for (int l = 0; l < 4; ++l){ sck[l] = ws + off; off += 1024; }
  __half* wPh[4];
  for (int l = 0; l < 4; ++l){ wPh[l] = (__half*)(ws + off); off += 131072; } // <=1024x256 fp16
  float* bP[4];
  for (int l = 0; l < 4; ++l){ bP[l] = ws + off; off += 1024; }
  __half* nlwh = (__half*)(ws + off); off += 32768;                           // 256x256 fp16
  __half* x0h = (__half*)(ws + off);  off += (size_t)26656*192/2;             // K padded to 192
  __half* G   = (__half*)(ws + off);  off += (size_t)28672*1024/2;
  __half* h0h = (__half*)(ws + off);  off += (size_t)26656*256/2;
  __half* h1h = (__half*)(ws + off);  off += (size_t)26656*256/2;
  float*  h1f = ws + off;             off += (size_t)26656*256;
  __half* h2h = (__half*)(ws + off);  off += (size_t)26656*256/2;
  __half* xfh = (__half*)(ws + off);  off += (size_t)26656*256/2;
  __half* xth = (__half*)(ws + off);  off += (size_t)26656*256/2;
  (void)ws_size; (void)in_sizes; (void)n_in; (void)out_size;

  levels_k<<<1, 64, 0, stream>>>(train, ism, levs);
  win_x_k<<<19992, 256, 0, stream>>>(train, levs, x0h);   // 833*32*192 / 256
  win_out_k<<<2499, 256, 0, stream>>>(train, levs, out + 639744);
  const int Kin[4]  = {168, 256, 256, 256};
  const int Kpad[4] = {192, 256, 256, 256};
  for (int l = 0; l < 4; ++l){
    packq_k<<<4, 256, 0, stream>>>(whh[l], wqk[l], sck[l]);
    permw_k<<<1024, 256, 0, stream>>>(wih[l], bih[l], bhh[l], wPh[l], bP[l], Kin[l], Kpad[l]);
  }
  cvth_k<<<256, 256, 0, stream>>>(nl_w, nlwh, 65536);

  // layer 0 (d=1): 833 steps, 32 rows -> 32 WGs x 1 row  (K padded to 192)
  proj_mfma<<<dim3(8,105), 512, 0, stream>>>((const _Float16*)x0h, (const _Float16*)wPh[0], bP[0], G, 26656, 192, 1024, 0, 0, 1);
  srecc_k<1><<<32, 256, 0, stream>>>(wqk[0], sck[0], G, h0h, nullptr, 833, 1, 32);
  // layer 1 (d=4): 209 steps, 128 rows -> 128 WGs x 1 row
  proj_mfma<<<dim3(8,105), 512, 0, stream>>>((const _Float16*)h0h, (const _Float16*)wPh[1], bP[1], G, 26752, 256, 1024, 4, 0, 1);
  srecc_k<1><<<128, 256, 0, stream>>>(wqk[1], sck[1], G, h1h, h1f, 209, 4, 128);
  // layer 2 (d=16): 53 steps, 512 rows -> 256 WGs x 2 rows
  proj_mfma<<<dim3(8,106), 512, 0, stream>>>((const _Float16*)h1h, (const _Float16*)wPh[2], bP[2], G, 27136, 256, 1024, 16, 0, 1);
  srecc_k<2><<<256, 256, 0, stream>>>(wqk[2], sck[2], G, h2h, nullptr, 53, 16, 512);
  // layer 3 (d=64): 14 steps, 2048 rows -> 256 WGs x 8 rows; residual h1f; fp16 out xfh
  proj_mfma<<<dim3(8,112), 512, 0, stream>>>((const _Float16*)h2h, (const _Float16*)wPh[3], bP[3], G, 28672, 256, 1024, 64, 0, 1);
  srecq_k<8><<<256, 1024, 0, stream>>>(wqk[3], sck[3], G, xfh, h1f, 14, 64, 2048);
  // nonlinear dense: xt = tanh(xf @ nl_w.T + nl_b)
  proj_mfma<<<dim3(2,105), 512, 0, stream>>>((const _Float16*)xfh, (const _Float16*)nlwh, nl_b, xth, 26656, 256, 256, 0, 1, 1);
  // scoring head -> pred (first half of d_out)
  sc_head<<<3332, 256, 0, stream>>>(xth, sc_w, sc_b, out, 26656);
}

// Round 21
// 1595.436 us; speedup vs baseline: 1.4840x; 1.4840x over previous
//
#include <hip/hip_runtime.h>
#include <hip/hip_fp16.h>
#include <math.h>

#define TT 833          // output timesteps
#define GDIM 1024       // 4*H gates

typedef _Float16 f16x8 __attribute__((ext_vector_type(8)));
typedef float    f32x4 __attribute__((ext_vector_type(4)));

#if __has_builtin(__builtin_amdgcn_rcpf)
__device__ __forceinline__ float frcp(float x){ return __builtin_amdgcn_rcpf(x); }
#else
__device__ __forceinline__ float frcp(float x){ return 1.f/x; }
#endif

#if __has_builtin(__builtin_amdgcn_sdot4)
__device__ __forceinline__ int sdot4(unsigned a, unsigned b, int c){
  return __builtin_amdgcn_sdot4((int)a, (int)b, c, false);
}
#else
__device__ __forceinline__ int sdot4(unsigned a, unsigned b, int c){
  int ai = (int)a, bi = (int)b;
  c += ((ai<<24)>>24)*((bi<<24)>>24);
  c += ((ai<<16)>>24)*((bi<<16)>>24);
  c += ((ai<<8)>>24)*((bi<<8)>>24);
  c += (ai>>24)*(bi>>24);
  return c;
}
#endif

// LDS-only barrier (r17): keeps per-step global h-stores off the serial path.
__device__ __forceinline__ void lds_barrier(){
  asm volatile("s_waitcnt lgkmcnt(0)" ::: "memory");
  __builtin_amdgcn_s_barrier();
  __builtin_amdgcn_sched_barrier(0);
}

// Gate-row permutation: permuted row p <-> original row (p&3)*256 + (p>>2).
// Recurrence: r15/r19 512-thread, 2 gate rows/thread — the empirical optimum
// (256-thr cell-per-thread spills/streams [r20]; 1024-thr doubles redundancy [r13]).

// ---------------- level smoothing scan (float4-batched) ----------------
__global__ void levels_k(const float* __restrict__ train, const float* __restrict__ ism,
                         float* __restrict__ levs){
  int b = threadIdx.x;
  if (b >= 32) return;
  float a = 1.f/(1.f+expf(-ism[0]));
  const float4* tr4 = reinterpret_cast<const float4*>(train + b*1024);
  float4* lv4 = reinterpret_cast<float4*>(levs + b*1024);
  float lev = 0.f;
  for (int i = 0; i < 256; ++i){
    float4 v = tr4[i];
    float4 o;
    if (i == 0) o.x = lev = fmaxf(v.x, 0.1f);
    else        o.x = lev = fmaxf(fmaf(a, v.x, (1.f-a)*lev), 0.1f);
    o.y = lev = fmaxf(fmaf(a, v.y, (1.f-a)*lev), 0.1f);
    o.z = lev = fmaxf(fmaf(a, v.z, (1.f-a)*lev), 0.1f);
    o.w = lev = fmaxf(fmaf(a, v.w, (1.f-a)*lev), 0.1f);
    lv4[i] = o;
  }
}

// ---------------- normalized input windows x0[t*32+b][192] fp16, zero-padded ----------------
__global__ void win_x_k(const float* __restrict__ train, const float* __restrict__ levs,
                        __half* __restrict__ x0){
  int idx = blockIdx.x*256 + threadIdx.x;   // exactly 833*32*192
  int i = idx % 192;
  int r = idx / 192;       // t*32+b
  int b = r & 31;
  int t = r >> 5;
  x0[idx] = (i < 168) ? __float2half(train[b*1024 + t + i] / levs[b*1024 + t + 167])
                      : __float2half(0.f);
}

// ---------------- out_win -> d_out second half ----------------
__global__ void win_out_k(const float* __restrict__ train, const float* __restrict__ levs,
                          float* __restrict__ ow){
  int idx = blockIdx.x*256 + threadIdx.x;   // exactly 833*32*24
  int o = idx % 24;
  int r = idx / 24;
  int b = r & 31;
  int t = r >> 5;
  ow[idx] = train[b*1024 + 168 + t + o] / levs[b*1024 + t + 167];
}

// ---------------- permute wih rows -> fp16 (Kpad stride, zero-pad) + fuse biases ----------
__global__ void permw_k(const float* __restrict__ wih, const float* __restrict__ bih,
                        const float* __restrict__ bhh, __half* __restrict__ wP,
                        float* __restrict__ bP, int K, int Kpad){
  int t = blockIdx.x;                       // 1024 rows
  int g = ((t & 3) << 8) + (t >> 2);
  for (int k = threadIdx.x; k < Kpad; k += 256)
    wP[(size_t)t*Kpad + k] = (k < K) ? __float2half(wih[(size_t)g*K + k]) : __float2half(0.f);
  if (threadIdx.x == 0) bP[t] = bih[g] + bhh[g];
}

// ---------------- fp32 -> fp16 convert (one-time, nl_w) ----------------
__global__ void cvth_k(const float* __restrict__ s, __half* __restrict__ d, int n){
  int i = blockIdx.x*256 + threadIdx.x;
  if (i < n) d[i] = __float2half(s[i]);
}

// ---------------- quantize whh -> int8 wq[k16][1024] permuted rows (+ scale) ----------------
__global__ void packq_k(const float* __restrict__ w, uint4* __restrict__ wq,
                        float* __restrict__ sc){
  int t = blockIdx.x*256 + threadIdx.x;     // 1024 rows
  if (t >= 1024) return;
  int g = ((t & 3) << 8) + (t >> 2);
  const float* row = w + (size_t)g*256;
  float amax = 0.f;
  for (int k = 0; k < 256; ++k) amax = fmaxf(amax, fabsf(row[k]));
  amax = fmaxf(amax, 1e-20f);
  float s = amax/127.f, inv = 127.f/amax;
  sc[t] = s;
  for (int k16 = 0; k16 < 16; ++k16){
    union { uint4 u; signed char b[16]; } r;
    #pragma unroll
    for (int j = 0; j < 16; ++j){
      float q = rintf(row[k16*16 + j]*inv);
      q = fminf(fmaxf(q, -127.f), 127.f);
      r.b[j] = (signed char)q;
    }
    wq[(size_t)k16*1024 + t] = r.u;
  }
}

// ---------------- MFMA fp16 GEMM, 256x128 tile, double-buffered LDS + reg prefetch -------
// One barrier per K-iter; iteration kt+1's global loads are issued right after the
// barrier so their latency hides under kt's 16 MFMAs (T14 idea applied in-kernel).
// K must be a multiple of 32 (buffers pre-padded).
__global__ __launch_bounds__(512) void proj_mfma(
    const _Float16* __restrict__ A, const _Float16* __restrict__ W,
    const float* __restrict__ b1,
    void* __restrict__ C, int Mout, int K, int N, int dil, int act, int outHalf)
{
  __shared__ _Float16 As[2][256*40];
  __shared__ _Float16 Bs[2][128*40];
  const int tid = threadIdx.x;
  const int lane = tid & 63;
  const int w = tid >> 6, wr = w >> 1, wc = w & 1;   // 4x2 wave grid
  const int m0 = blockIdx.y << 8, n0 = blockIdx.x << 7;

  const int rowA = tid >> 1;
  const int halfsel = tid & 1;
  int srcrow;
  {
    int m = m0 + rowA;
    if (dil == 0) srcrow = (m < Mout) ? m : -1;
    else {
      int rows = dil << 5;
      int jj = m / rows;
      int q = m - jj*rows;
      int t = jj*dil + (q >> 5);
      srcrow = (t < TT) ? ((t << 5) + (q & 31)) : -1;
    }
  }
  const int rowB = (tid & 255) >> 1;
  const int nrow = n0 + rowB;

  f32x4 acc[4][4];
  #pragma unroll
  for (int i = 0; i < 4; ++i)
    #pragma unroll
    for (int j = 0; j < 4; ++j) acc[i][j] = (f32x4){0.f,0.f,0.f,0.f};

  uint4 ta0, ta1, tb0 = make_uint4(0,0,0,0), tb1 = make_uint4(0,0,0,0);
  auto loadK = [&](int kt){
    const int k0 = (kt << 5) + halfsel*16;
    if (srcrow >= 0){
      const uint4* s = reinterpret_cast<const uint4*>(A + (size_t)srcrow*K + k0);
      ta0 = s[0]; ta1 = s[1];
    } else { ta0 = make_uint4(0,0,0,0); ta1 = make_uint4(0,0,0,0); }
    if (tid < 256){
      const uint4* s = reinterpret_cast<const uint4*>(W + (size_t)nrow*K + k0);
      tb0 = s[0]; tb1 = s[1];
    }
  };

  const int nkt = K >> 5;
  loadK(0);
  for (int kt = 0; kt < nkt; ++kt){
    const int buf = kt & 1;
    {
      uint4* dst = reinterpret_cast<uint4*>(&As[buf][rowA*40 + halfsel*16]);
      dst[0] = ta0; dst[1] = ta1;
    }
    if (tid < 256){
      uint4* dst = reinterpret_cast<uint4*>(&Bs[buf][rowB*40 + halfsel*16]);
      dst[0] = tb0; dst[1] = tb1;
    }
    __syncthreads();
    if (kt + 1 < nkt) loadK(kt + 1);   // prefetch overlaps this iteration's MFMAs
    {
      const int kg = lane >> 4, r16 = lane & 15;
      f16x8 af[4], bf[4];
      #pragma unroll
      for (int mi = 0; mi < 4; ++mi)
        af[mi] = *reinterpret_cast<const f16x8*>(&As[buf][(wr*64 + mi*16 + r16)*40 + kg*8]);
      #pragma unroll
      for (int nj = 0; nj < 4; ++nj)
        bf[nj] = *reinterpret_cast<const f16x8*>(&Bs[buf][(wc*64 + nj*16 + r16)*40 + kg*8]);
      #pragma unroll
      for (int mi = 0; mi < 4; ++mi)
        #pragma unroll
        for (int nj = 0; nj < 4; ++nj)
          acc[mi][nj] = __builtin_amdgcn_mfma_f32_16x16x32_f16(af[mi], bf[nj], acc[mi][nj], 0, 0, 0);
    }
  }
  #pragma unroll
  for (int mi = 0; mi < 4; ++mi){
    #pragma unroll
    for (int p = 0; p < 4; ++p){
      int mrow = m0 + wr*64 + mi*16 + (lane >> 4)*4 + p;
      if (mrow >= Mout) continue;
      #pragma unroll
      for (int nj = 0; nj < 4; ++nj){
        int ncol = n0 + wc*64 + nj*16 + (lane & 15);
        float v = acc[mi][nj][p] + b1[ncol];
        if (act) v = tanhf(v);
        if (outHalf) reinterpret_cast<__half*>(C)[(size_t)mrow*N + ncol] = __float2half(v);
        else reinterpret_cast<float*>(C)[(size_t)mrow*N + ncol] = v;
      }
    }
  }
}

// ---------------- 512-thread register-weight int8 sdot4 LSTM (2 gate rows/thread) --------
template<int NR>
__global__ __launch_bounds__(512, 1) void srecr2_k(
    const uint4* __restrict__ wq, const float* __restrict__ scale,
    const __half* __restrict__ Gin,
    __half* __restrict__ outh, float* __restrict__ outf,
    int nsteps, int d, int rowsTotal)
{
  __shared__ __align__(16) unsigned int hq[2][NR][64];
  const int tid = threadIdx.x;       // 0..511
  const int s = tid & 1;             // 0: gates i,f   1: gates g,o
  const int j = tid >> 1;            // cell index 0..255
  const int q0 = blockIdx.x*NR;
  const float sg0 = scale[2*tid]*(1.f/127.f);
  const float sg1 = scale[2*tid + 1]*(1.f/127.f);
  uint4 w0_[16], w1_[16];
  #pragma unroll
  for (int kk = 0; kk < 16; ++kk){
    w0_[kk] = wq[(size_t)kk*1024 + 2*tid];
    w1_[kk] = wq[(size_t)kk*1024 + 2*tid + 1];
  }
  float c[NR];
  #pragma unroll
  for (int rr = 0; rr < NR; ++rr) c[rr] = 0.f;
  for (int e = tid; e < 2*NR*64; e += 512) (&hq[0][0][0])[e] = 0u;
  __syncthreads();

  for (int step = 0; step < nsteps; ++step){
    const int cur = step & 1;
    const __half2* gbase = reinterpret_cast<const __half2*>(
        Gin + ((size_t)step*rowsTotal + q0)*GDIM);
    #pragma unroll
    for (int rr = 0; rr < NR; ++rr){
      __half2 g2 = gbase[rr*512 + tid];
      float gin0 = __half2float(__low2half(g2));
      float gin1 = __half2float(__high2half(g2));
      int a00 = 0, a01 = 0, a10 = 0, a11 = 0;
      #pragma unroll
      for (int k16 = 0; k16 < 8; ++k16){
        uint4 ha = *reinterpret_cast<const uint4*>(&hq[cur][rr][4*k16]);
        a00 = sdot4(w0_[k16].x, ha.x, a00); a00 = sdot4(w0_[k16].y, ha.y, a00);
        a00 = sdot4(w0_[k16].z, ha.z, a00); a00 = sdot4(w0_[k16].w, ha.w, a00);
        a10 = sdot4(w1_[k16].x, ha.x, a10); a10 = sdot4(w1_[k16].y, ha.y, a10);
        a10 = sdot4(w1_[k16].z, ha.z, a10); a10 = sdot4(w1_[k16].w, ha.w, a10);
        uint4 hb = *reinterpret_cast<const uint4*>(&hq[cur][rr][4*(k16 + 8)]);
        a01 = sdot4(w0_[k16+8].x, hb.x, a01); a01 = sdot4(w0_[k16+8].y, hb.y, a01);
        a01 = sdot4(w0_[k16+8].z, hb.z, a01); a01 = sdot4(w0_[k16+8].w, hb.w, a01);
        a11 = sdot4(w1_[k16+8].x, hb.x, a11); a11 = sdot4(w1_[k16+8].y, hb.y, a11);
        a11 = sdot4(w1_[k16+8].z, hb.z, a11); a11 = sdot4(w1_[k16+8].w, hb.w, a11);
      }
      float p0 = fmaf((float)(a00 + a01), sg0, gin0);
      float p1 = fmaf((float)(a10 + a11), sg1, gin1);
      float px0 = s ? p0 + p0 : p0;
      float t0 = frcp(1.f + __expf(-px0));
      float a0v = s ? fmaf(2.f, t0, -1.f) : t0;
      float a1v = frcp(1.f + __expf(-p1));
      float b0 = __shfl_xor(a0v, 1);
      float b1 = __shfl_xor(a1v, 1);
      float iv = s ? b0 : a0v;
      float fv = s ? b1 : a1v;
      float gv = s ? a0v : b0;
      float ov = s ? a1v : b1;
      float cn = fmaf(fv, c[rr], iv*gv);
      c[rr] = cn;
      if (s == 0){
        float e2 = __expf(-2.f*cn);
        float h = ov*(1.f - e2)*frcp(1.f + e2);
        int qh = (int)rintf(h*127.f);
        reinterpret_cast<signed char*>(&hq[cur^1][rr][0])[j] = (signed char)qh;
        int q = q0 + rr;
        int tg = step*d + (q >> 5);
        if (tg < TT){
          size_t oi = ((size_t)tg*32 + (q & 31))*256 + j;
          outh[oi] = __float2half(h);
          if (outf) outf[oi] = h;
        }
      }
    }
    lds_barrier();
  }
}

// ---------------- streamed-weight variant (NR=8, d=64), residual, fp16 out --------------
template<int NR>
__global__ __launch_bounds__(1024) void srecq_k(
    const uint4* __restrict__ wq, const float* __restrict__ scale,
    const __half* __restrict__ Gin,
    __half* __restrict__ outh, const float* __restrict__ res,
    int nsteps, int d, int rowsTotal)
{
  __shared__ __align__(16) unsigned int hq[2][NR][64];
  const int tid = threadIdx.x;
  const int lane = tid & 63;
  const int base = lane & ~3;
  const int kg = tid & 3;
  const int j = tid >> 2;
  const int q0 = blockIdx.x*NR;
  const float sg = scale[tid]*(1.f/127.f);
  float c[NR];
  #pragma unroll
  for (int rr = 0; rr < NR; ++rr) c[rr] = 0.f;
  for (int e = tid; e < 2*NR*64; e += 1024) (&hq[0][0][0])[e] = 0u;
  __syncthreads();

  for (int step = 0; step < nsteps; ++step){
    const int cur = step & 1;
    float gin[NR];
    const __half* gbase = Gin + ((size_t)step*rowsTotal + q0)*GDIM;
    #pragma unroll
    for (int rr = 0; rr < NR; ++rr) gin[rr] = __half2float(gbase[rr*GDIM + tid]);
    int acc[NR];
    #pragma unroll
    for (int rr = 0; rr < NR; ++rr) acc[rr] = 0;
    #pragma unroll 4
    for (int k16 = 0; k16 < 16; ++k16){
      uint4 w = wq[(size_t)k16*1024 + tid];
      #pragma unroll
      for (int rr = 0; rr < NR; ++rr){
        uint4 h4 = *reinterpret_cast<const uint4*>(&hq[cur][rr][4*k16]);
        acc[rr] = sdot4(w.x, h4.x, acc[rr]);
        acc[rr] = sdot4(w.y, h4.y, acc[rr]);
        acc[rr] = sdot4(w.z, h4.z, acc[rr]);
        acc[rr] = sdot4(w.w, h4.w, acc[rr]);
      }
    }
    #pragma unroll
    for (int rr = 0; rr < NR; ++rr){
      float p = fmaf((float)acc[rr], sg, gin[rr]);
      float px = (kg == 2) ? p + p : p;
      float sv = frcp(1.f + __expf(-px));
      float a = (kg == 2) ? fmaf(2.f, sv, -1.f) : sv;
      float iv = __shfl(a, base + 0);
      float fv = __shfl(a, base + 1);
      float gv = __shfl(a, base + 2);
      float ov = __shfl(a, base + 3);
      float cn = fmaf(fv, c[rr], iv*gv);
      c[rr] = cn;
      float e2 = __expf(-2.f*cn);
      float h = ov*(1.f - e2)*frcp(1.f + e2);
      if (kg == 0){
        int qh = (int)rintf(h*127.f);
        reinterpret_cast<signed char*>(&hq[cur^1][rr][0])[j] = (signed char)qh;
        int q = q0 + rr;
        int tg = step*d + (q >> 5);
        if (tg < TT){
          size_t oi = ((size_t)tg*32 + (q & 31))*256 + j;
          outh[oi] = __float2half(h + res[oi]);
        }
      }
    }
    lds_barrier();
  }
}

// ---------------- scoring head (fp16 xt): pred[m][24] = xt[m][:] . sc_w[n][:] + sc_b ------
__global__ __launch_bounds__(256) void sc_head(const __half* __restrict__ xt, const float* __restrict__ w,
                        const float* __restrict__ bias, float* __restrict__ outp, int M){
  __shared__ float arow[8][256];
  int m0 = blockIdx.x << 3;
  int tid = threadIdx.x;
  #pragma unroll
  for (int i = 0; i < 8; ++i){
    int e = tid + (i << 8);
    int r = e >> 8, k = e & 255;
    arow[r][k] = (m0 + r < M) ? __half2float(xt[(size_t)(m0 + r)*256 + k]) : 0.f;
  }
  __syncthreads();
  int r = tid >> 5, n = tid & 31;
  if (n < 24 && (m0 + r) < M){
    float acc = bias[n];
    const float* wr = w + n*256;
    #pragma unroll 8
    for (int k = 0; k < 256; ++k) acc = fmaf(arow[r][k], wr[k], acc);
    outp[(size_t)(m0 + r)*24 + n] = acc;
  }
}

extern "C" void kernel_launch(void* const* d_in, const int* in_sizes, int n_in,
                              void* d_out, int out_size, void* d_ws, size_t ws_size,
                              hipStream_t stream){
  const float* train = (const float*)d_in[0];
  const float* ism   = (const float*)d_in[4];
  const float* wih[4] = {(const float*)d_in[5], (const float*)d_in[9], (const float*)d_in[13], (const float*)d_in[17]};
  const float* whh[4] = {(const float*)d_in[6], (const float*)d_in[10], (const float*)d_in[14], (const float*)d_in[18]};
  const float* bih[4] = {(const float*)d_in[7], (const float*)d_in[11], (const float*)d_in[15], (const float*)d_in[19]};
  const float* bhh[4] = {(const float*)d_in[8], (const float*)d_in[12], (const float*)d_in[16], (const float*)d_in[20]};
  const float* nl_w = (const float*)d_in[21];
  const float* nl_b = (const float*)d_in[22];
  const float* sc_w = (const float*)d_in[23];
  const float* sc_b = (const float*)d_in[24];
  float* out = (float*)d_out;

  float* ws = (float*)d_ws;
  size_t off = 0;
  float* levs = ws + off;   off += 32768;
  uint4* wqk[4];
  for (int l = 0; l < 4; ++l){ wqk[l] = (uint4*)(ws + off); off += 65536; }   // 256KB each
  float* sck[4];
  for (int l = 0; l < 4; ++l){ sck[l] = ws + off; off += 1024; }
  __half* wPh[4];
  for (int l = 0; l < 4; ++l){ wPh[l] = (__half*)(ws + off); off += 131072; } // <=1024x256 fp16
  float* bP[4];
  for (int l = 0; l < 4; ++l){ bP[l] = ws + off; off += 1024; }
  __half* nlwh = (__half*)(ws + off); off += 32768;                           // 256x256 fp16
  __half* x0h = (__half*)(ws + off);  off += (size_t)26656*192/2;             // K padded to 192
  __half* G   = (__half*)(ws + off);  off += (size_t)28672*1024/2;
  __half* h0h = (__half*)(ws + off);  off += (size_t)26656*256/2;
  __half* h1h = (__half*)(ws + off);  off += (size_t)26656*256/2;
  float*  h1f = ws + off;             off += (size_t)26656*256;
  __half* h2h = (__half*)(ws + off);  off += (size_t)26656*256/2;
  __half* xfh = (__half*)(ws + off);  off += (size_t)26656*256/2;
  __half* xth = (__half*)(ws + off);  off += (size_t)26656*256/2;
  (void)ws_size; (void)in_sizes; (void)n_in; (void)out_size;

  levels_k<<<1, 64, 0, stream>>>(train, ism, levs);
  win_x_k<<<19992, 256, 0, stream>>>(train, levs, x0h);   // 833*32*192 / 256
  win_out_k<<<2499, 256, 0, stream>>>(train, levs, out + 639744);
  const int Kin[4]  = {168, 256, 256, 256};
  const int Kpad[4] = {192, 256, 256, 256};
  for (int l = 0; l < 4; ++l){
    packq_k<<<4, 256, 0, stream>>>(whh[l], wqk[l], sck[l]);
    permw_k<<<1024, 256, 0, stream>>>(wih[l], bih[l], bhh[l], wPh[l], bP[l], Kin[l], Kpad[l]);
  }
  cvth_k<<<256, 256, 0, stream>>>(nl_w, nlwh, 65536);

  // layer 0 (d=1): 833 steps, 32 rows -> 32 WGs x 1 row  (K padded to 192)
  proj_mfma<<<dim3(8,105), 512, 0, stream>>>((const _Float16*)x0h, (const _Float16*)wPh[0], bP[0], G, 26656, 192, 1024, 0, 0, 1);
  srecr2_k<1><<<32, 512, 0, stream>>>(wqk[0], sck[0], G, h0h, nullptr, 833, 1, 32);
  // layer 1 (d=4): 209 steps, 128 rows -> 128 WGs x 1 row
  proj_mfma<<<dim3(8,105), 512, 0, stream>>>((const _Float16*)h0h, (const _Float16*)wPh[1], bP[1], G, 26752, 256, 1024, 4, 0, 1);
  srecr2_k<1><<<128, 512, 0, stream>>>(wqk[1], sck[1], G, h1h, h1f, 209, 4, 128);
  // layer 2 (d=16): 53 steps, 512 rows -> 256 WGs x 2 rows
  proj_mfma<<<dim3(8,106), 512, 0, stream>>>((const _Float16*)h1h, (const _Float16*)wPh[2], bP[2], G, 27136, 256, 1024, 16, 0, 1);
  srecr2_k<2><<<256, 512, 0, stream>>>(wqk[2], sck[2], G, h2h, nullptr, 53, 16, 512);
  // layer 3 (d=64): 14 steps, 2048 rows -> 256 WGs x 8 rows; residual h1f; fp16 out xfh
  proj_mfma<<<dim3(8,112), 512, 0, stream>>>((const _Float16*)h2h, (const _Float16*)wPh[3], bP[3], G, 28672, 256, 1024, 64, 0, 1);
  srecq_k<8><<<256, 1024, 0, stream>>>(wqk[3], sck[3], G, xfh, h1f, 14, 64, 2048);
  // nonlinear dense: xt = tanh(xf @ nl_w.T + nl_b)
  proj_mfma<<<dim3(2,105), 512, 0, stream>>>((const _Float16*)xfh, (const _Float16*)nlwh, nl_b, xth, 26656, 256, 256, 0, 1, 1);
  // scoring head -> pred (first half of d_out)
  sc_head<<<3332, 256, 0, stream>>>(xth, sc_w, sc_b, out, 26656);
}